// Round 10
// baseline (52.703 us; speedup 1.0000x reference)
//
#include <hip/hip_runtime.h>

#define N_ROWS 14400
#define M_COLS 1600
#define KDIM   256
#define GRID_X 25           // 1600 / 64 col-tiles (exact)
#define GRID_Y 113          // ceil(14400/128) row-tiles
#define NWG    (GRID_X * GRID_Y)   // 2825

typedef __attribute__((ext_vector_type(8))) short bf16x8;
typedef __attribute__((ext_vector_type(4))) float f32x4;

__device__ __forceinline__ short f2bf(float x) {
  union { float f; unsigned u; } v; v.f = x;
  unsigned r = v.u + 0x7FFFu + ((v.u >> 16) & 1u);   // RNE to bf16
  return (short)(r >> 16);
}

__device__ __forceinline__ void gload_lds16(const void* g, void* l) {
  __builtin_amdgcn_global_load_lds(
      (const __attribute__((address_space(1))) void*)g,
      (__attribute__((address_space(3))) void*)l, 16, 0, 0);
}

// One WAVE per row; lane handles 4 consecutive floats (float4 in, short4 out).
__global__ __launch_bounds__(256) void prep_kernel(
    const float* __restrict__ logits, const float* __restrict__ embs,
    short* __restrict__ probB, short* __restrict__ embB) {
  const int row = blockIdx.x * 4 + (threadIdx.x >> 6);
  const int lane = threadIdx.x & 63;
  if (row < N_ROWS) {
    const float4 x = ((const float4*)(logits + (size_t)row * KDIM))[lane];
    float s = x.x * x.x + x.y * x.y + x.z * x.z + x.w * x.w;
#pragma unroll
    for (int o = 32; o > 0; o >>= 1) s += __shfl_xor(s, o, 64);
    const float scale = __builtin_amdgcn_rsqf(s);
    short4 o4;
    o4.x = f2bf(x.x * scale); o4.y = f2bf(x.y * scale);
    o4.z = f2bf(x.z * scale); o4.w = f2bf(x.w * scale);
    ((short4*)(probB + (size_t)row * KDIM))[lane] = o4;
  } else {
    const int r = row - N_ROWS;   // grid sized exactly, no overflow
    const float4 x = ((const float4*)(embs + (size_t)r * KDIM))[lane];
    short4 o4;
    o4.x = f2bf(x.x); o4.y = f2bf(x.y); o4.z = f2bf(x.z); o4.w = f2bf(x.w);
    ((short4*)(embB + (size_t)r * KDIM))[lane] = o4;
  }
}

// 128x64 tile GEMM (bf16 MFMA) + fused bbox-L1 + GIoU + sigmoid epilogue.
// r10: T3 minimum 2-phase K-loop. BK=32, double-buffered As/Bs (30 KB LDS
// total). Per iter: STAGE(next) -> ds_read+MFMA(cur) -> ONE __syncthreads.
// Loads are in flight during compute (r9's loop staged then immediately
// barriered - a full L2-latency bubble per iter).
// - 64-B-row XOR swizzle: store granule (t&3)^((t>>3)&3), read slot
//   (lane>>4)^((lane>>1)&3) -> 2-way aliasing (free).
// - acc[4][2] = 32 AGPR; no min-waves clamp (r2/r4 lesson).
// - Epilogue identical to r9: ping-pong tbuf, lgkm-only barriers, dwordx4
//   NT stores never drained mid-epilogue.
// - Bijective XCD-aware block swizzle for A-panel L2 reuse.
__global__ __launch_bounds__(256) void cost_kernel(
    const short* __restrict__ probB, const short* __restrict__ embB,
    const float* __restrict__ pbox, const float* __restrict__ tbox,
    float* __restrict__ out) {
  __shared__ short As2[2][128 * 32];   // 16 KB; tbuf overlays in epilogue
  __shared__ short Bs2[2][64 * 32];    // 8 KB
  __shared__ f32x4 rowcc[128], rowxy[128];   // 4 KB
  __shared__ f32x4 colcc[64],  colxy[64];    // 2 KB
  float* const tbuf = (float*)As2;     // 2 x [32][68] floats = 17408 B

  const int t = threadIdx.x;
  const int lane = t & 63;
  const int wid = t >> 6;
  const int wr = wid >> 1;          // wave row 0..1 (64-row band)
  const int wc = wid & 1;           // wave col 0..1 (32-col band)

  // Bijective XCD swizzle (m204): 8 XCDs, NWG=2825 (q=353, r=1).
  const int orig = blockIdx.x;
  const int xcd = orig & 7;
  const int rem = orig >> 3;
  const int q = NWG >> 3, r = NWG & 7;
  const int wgid = (xcd < r ? xcd * (q + 1) : r * (q + 1) + (xcd - r) * q) + rem;
  const int bx = wgid % GRID_X;
  const int by = wgid / GRID_X;
  const int rowBase = by * 128;     // N (pred) direction
  const int colBase = bx * 64;      // M (tgt) direction; always in-range

  // Stage per-tile box data (cols need no clamp: 1600 % 64 == 0).
  if (t < 128) {
    const int idx = rowBase + t;
    const int ci = idx < N_ROWS ? idx : N_ROWS - 1;
    const float4 bb = ((const float4*)pbox)[ci];
    rowcc[t] = (f32x4){bb.x, bb.y, bb.z, bb.w};
    rowxy[t] = (f32x4){fmaf(-0.5f, bb.z, bb.x), fmaf(-0.5f, bb.w, bb.y),
                       fmaf(0.5f, bb.z, bb.x), fmaf(0.5f, bb.w, bb.y)};
  } else if (t < 192) {
    const int c = t - 128;
    const float4 bb = ((const float4*)tbox)[colBase + c];
    colcc[c] = (f32x4){bb.x, bb.y, bb.z, bb.w};
    colxy[c] = (f32x4){fmaf(-0.5f, bb.z, bb.x), fmaf(-0.5f, bb.w, bb.y),
                       fmaf(0.5f, bb.z, bb.x), fmaf(0.5f, bb.w, bb.y)};
  }

  f32x4 acc[4][2];
#pragma unroll
  for (int i = 0; i < 4; ++i)
#pragma unroll
    for (int j = 0; j < 2; ++j) acc[i][j] = (f32x4){0.f, 0.f, 0.f, 0.f};

  // Staging geometry (BK=32, 64-B rows): thread t covers row t>>2, 16-B slot
  // t&3; pre-swizzled global granule (t&3)^((t>>3)&3) so reads at slot
  // (g ^ ((row>>1)&3)) see linear data, spread 2-way across banks.
  const int srow = t >> 2;                       // 0..63
  const int sgran = (t & 3) ^ ((t >> 3) & 3);    // source granule 0..3
  const int adest = wid * 16 * 32;               // wave-uniform dest (shorts)

  // Clamped A source rows for the two 64-row chunks (col rows need no clamp).
  int garow0 = rowBase + srow;        if (garow0 > N_ROWS - 1) garow0 = N_ROWS - 1;
  int garow1 = rowBase + 64 + srow;   if (garow1 > N_ROWS - 1) garow1 = N_ROWS - 1;
  const int gbrow = colBase + srow;

#define STAGE(kt_, buf_)                                                      \
  {                                                                           \
    const int k0_ = (kt_)*32 + sgran * 8;                                     \
    gload_lds16(probB + (size_t)garow0 * KDIM + k0_, &As2[buf_][adest]);      \
    gload_lds16(probB + (size_t)garow1 * KDIM + k0_,                          \
                &As2[buf_][64 * 32 + adest]);                                 \
    gload_lds16(embB + (size_t)gbrow * KDIM + k0_, &Bs2[buf_][adest]);        \
  }

  // Prologue: stage K-tile 0 into buf 0.
  STAGE(0, 0)
  __syncthreads();

  const int slot = (lane >> 4) ^ ((lane >> 1) & 3);  // read slot per lane
  const int arow = wr * 64 + (lane & 15);            // A fragment base row
  const int brow = wc * 32 + (lane & 15);            // B fragment base row

  // K-loop: 8 tiles of BK=32, 2-phase (stage next while computing current).
#pragma unroll
  for (int kt = 0; kt < 8; ++kt) {
    const int buf = kt & 1;
    if (kt < 7) STAGE(kt + 1, (kt + 1) & 1)
    bf16x8 af[4], bfr[2];
#pragma unroll
    for (int mi = 0; mi < 4; ++mi)
      af[mi] = *(const bf16x8*)(&As2[buf][(arow + mi * 16) * 32 + slot * 8]);
#pragma unroll
    for (int ni = 0; ni < 2; ++ni)
      bfr[ni] = *(const bf16x8*)(&Bs2[buf][(brow + ni * 16) * 32 + slot * 8]);
#pragma unroll
    for (int mi = 0; mi < 4; ++mi)
#pragma unroll
      for (int ni = 0; ni < 2; ++ni)
        acc[mi][ni] = __builtin_amdgcn_mfma_f32_16x16x32_bf16(
            af[mi], bfr[ni], acc[mi][ni], 0, 0, 0);
    __syncthreads();   // staging of kt+1 done block-wide; cur buf reusable
  }

  // Fused epilogue (r9): per mi compute+sigmoid -> tbuf[mi&1] (transpose)
  // -> lgkm-only barrier -> coalesced dwordx4 NT stores (never drained).
  const float LOG2E = 1.44269504f;
  const int jr = (lane >> 4) * 4;   // row sub-offset for this lane group
  const int lc = lane & 15;
  f32x4 c0v[2], c1v[2];
  float cav[2];
#pragma unroll
  for (int ni = 0; ni < 2; ++ni) {
    const int cloc = wc * 32 + ni * 16 + lc;
    c0v[ni] = colcc[cloc];
    c1v[ni] = colxy[cloc];
    cav[ni] = c0v[ni][2] * c0v[ni][3];
  }

#pragma unroll
  for (int mi = 0; mi < 4; ++mi) {
    float* const tb = tbuf + (mi & 1) * 2176;   // 32*68 floats per buffer
#pragma unroll
    for (int j = 0; j < 4; ++j) {
      const int rloc = wr * 64 + mi * 16 + jr + j;
      const f32x4 r0 = rowcc[rloc];
      const f32x4 r1 = rowxy[rloc];
      const float ra = r0[2] * r0[3];
#pragma unroll
      for (int ni = 0; ni < 2; ++ni) {
        const f32x4 c0 = c0v[ni], c1 = c1v[ni];
        const float cc = fmaxf(acc[mi][ni][j], 0.0f);
        const float l1 = fabsf(r0[0] - c0[0]) + fabsf(r0[1] - c0[1]) +
                         fabsf(r0[2] - c0[2]) + fabsf(r0[3] - c0[3]);
        const float ltx = fmaxf(r1[0], c1[0]);
        const float lty = fmaxf(r1[1], c1[1]);
        const float rbx = fminf(r1[2], c1[2]);
        const float rby = fminf(r1[3], c1[3]);
        const float iw = fmaxf(rbx - ltx, 0.f);
        const float ih = fmaxf(rby - lty, 0.f);
        const float inter = iw * ih;
        const float uni = ra + cav[ni] - inter;
        const float ex = fmaxf(r1[2], c1[2]) - fminf(r1[0], c1[0]);
        const float ey = fmaxf(r1[3], c1[3]) - fminf(r1[1], c1[1]);
        const float earea = ex * ey;
        // inter/uni + uni/earea = (inter*earea + uni^2) / (uni*earea)
        const float num = fmaf(uni, uni, inter * earea);
        const float Cv = l1 + cc + 1.0f
                         - num * __builtin_amdgcn_rcpf(uni * earea);
        const float sg = __builtin_amdgcn_rcpf(
            1.0f + __builtin_amdgcn_exp2f(-LOG2E * Cv));
        tb[(wr * 16 + jr + j) * 68 + wc * 32 + ni * 16 + lc] = sg;
      }
    }
    // lgkm-only block barrier: LDS writes visible, NT stores keep streaming.
    asm volatile("s_waitcnt lgkmcnt(0)" ::: "memory");
    __builtin_amdgcn_s_barrier();
    // Read back transposed chunk (32 rows x 64 cols) and stream out.
#pragma unroll
    for (int rr = 0; rr < 2; ++rr) {
      const int rch = rr * 16 + (t >> 4);    // 0..31
      const int c4 = (t & 15) * 4;           // 0..60
      const f32x4 v = *(const f32x4*)(tb + rch * 68 + c4);
      const int grow = rowBase + ((rch < 16) ? (mi * 16 + rch)
                                             : (64 + mi * 16 + (rch - 16)));
      if (grow < N_ROWS)
        __builtin_nontemporal_store(
            v, (f32x4*)(out + (size_t)grow * M_COLS + colBase + c4));
    }
    // No second barrier: next mi writes the OTHER buffer; its pre-barrier
    // lgkmcnt(0) covers every wave's reads of this one.
  }
#undef STAGE
}

extern "C" void kernel_launch(void* const* d_in, const int* in_sizes, int n_in,
                              void* d_out, int out_size, void* d_ws, size_t ws_size,
                              hipStream_t stream) {
  const float* logits = (const float*)d_in[0];   // [16,900,256]
  const float* pbox   = (const float*)d_in[1];   // [16,900,4]
  const float* embs   = (const float*)d_in[2];   // [1600,256]
  const float* tbox   = (const float*)d_in[3];   // [1600,4]
  float* out = (float*)d_out;                    // [16,900,1600]

  short* probB = (short*)d_ws;                         // 14400*256 bf16
  short* embB  = probB + (size_t)N_ROWS * KDIM;        // 1600*256 bf16

  prep_kernel<<<(N_ROWS + M_COLS) / 4, 256, 0, stream>>>(logits, embs, probB, embB);

  cost_kernel<<<NWG, 256, 0, stream>>>(probB, embB, pbox, tbox, out);
}

// Round 11
// 48.114 us; speedup vs baseline: 1.0954x; 1.0954x over previous
//
#include <hip/hip_runtime.h>

#define N_ROWS 14400
#define M_COLS 1600
#define KDIM   256
#define GRID_X 25           // 1600 / 64 col-tiles (exact)
#define GRID_Y 113          // ceil(14400/128) row-tiles
#define NWG    (GRID_X * GRID_Y)   // 2825

typedef __attribute__((ext_vector_type(8))) short bf16x8;
typedef __attribute__((ext_vector_type(4))) float f32x4;

__device__ __forceinline__ short f2bf(float x) {
  union { float f; unsigned u; } v; v.f = x;
  unsigned r = v.u + 0x7FFFu + ((v.u >> 16) & 1u);   // RNE to bf16
  return (short)(r >> 16);
}

__device__ __forceinline__ void gload_lds16(const void* g, void* l) {
  __builtin_amdgcn_global_load_lds(
      (const __attribute__((address_space(1))) void*)g,
      (__attribute__((address_space(3))) void*)l, 16, 0, 0);
}

// One WAVE per row; lane handles 4 consecutive floats (float4 in, short4 out).
__global__ __launch_bounds__(256) void prep_kernel(
    const float* __restrict__ logits, const float* __restrict__ embs,
    short* __restrict__ probB, short* __restrict__ embB) {
  const int row = blockIdx.x * 4 + (threadIdx.x >> 6);
  const int lane = threadIdx.x & 63;
  if (row < N_ROWS) {
    const float4 x = ((const float4*)(logits + (size_t)row * KDIM))[lane];
    float s = x.x * x.x + x.y * x.y + x.z * x.z + x.w * x.w;
#pragma unroll
    for (int o = 32; o > 0; o >>= 1) s += __shfl_xor(s, o, 64);
    const float scale = __builtin_amdgcn_rsqf(s);
    short4 o4;
    o4.x = f2bf(x.x * scale); o4.y = f2bf(x.y * scale);
    o4.z = f2bf(x.z * scale); o4.w = f2bf(x.w * scale);
    ((short4*)(probB + (size_t)row * KDIM))[lane] = o4;
  } else {
    const int r = row - N_ROWS;   // grid sized exactly, no overflow
    const float4 x = ((const float4*)(embs + (size_t)r * KDIM))[lane];
    short4 o4;
    o4.x = f2bf(x.x); o4.y = f2bf(x.y); o4.z = f2bf(x.z); o4.w = f2bf(x.w);
    ((short4*)(embB + (size_t)r * KDIM))[lane] = o4;
  }
}

// 128x64 tile GEMM (bf16 MFMA) + fused bbox-L1 + GIoU + sigmoid epilogue.
// r11 = r9 (best: 48.8 us) + enclosing-box min/max sum identity:
//   max(a,b)+min(a,b)=a+b  =>  ex = (rw+cw) - iwx_unclamped  (w,h >= 0)
// removing 4 min/max per element (34 -> 32 VALU).
// Proven pieces kept verbatim:
// - acc[4][2] = 32 AGPR; VGPR compiler-chosen ~96 (every run with VGPR<=64
//   regressed ~10us: r2/r4/r10).
// - LDS GEMM tiles XOR-swizzled -> 0 bank conflicts.
// - Ping-pong tbuf transpose + lgkm-only epilogue barriers; dwordx4 NT
//   stores (WRITE_SIZE exactly 90000 KB, zero amplification).
// - Bijective XCD-aware block swizzle (FETCH ~7 MB, inputs L2-resident).
__global__ __launch_bounds__(256) void cost_kernel(
    const short* __restrict__ probB, const short* __restrict__ embB,
    const float* __restrict__ pbox, const float* __restrict__ tbox,
    float* __restrict__ out) {
  __shared__ short As[128 * 64];    // 16 KB; tbuf ping-pong overlays As+Bs
  __shared__ short Bs[64 * 64];     // 8 KB
  __shared__ f32x4 rowcc[128], rowxy[128];   // 4 KB
  __shared__ f32x4 colcc[64],  colxy[64];    // 2 KB
  float* const tbuf = (float*)As;   // 2 x [32][68] floats = 17408 B

  const int t = threadIdx.x;
  const int lane = t & 63;
  const int wid = t >> 6;
  const int wr = wid >> 1;          // wave row 0..1 (64-row band)
  const int wc = wid & 1;           // wave col 0..1 (32-col band)

  // Bijective XCD swizzle (m204): 8 XCDs, NWG=2825 (q=353, r=1).
  const int orig = blockIdx.x;
  const int xcd = orig & 7;
  const int rem = orig >> 3;
  const int q = NWG >> 3, r = NWG & 7;
  const int wgid = (xcd < r ? xcd * (q + 1) : r * (q + 1) + (xcd - r) * q) + rem;
  const int bx = wgid % GRID_X;
  const int by = wgid / GRID_X;
  const int rowBase = by * 128;     // N (pred) direction
  const int colBase = bx * 64;      // M (tgt) direction; always in-range

  // Stage per-tile box data (cols need no clamp: 1600 % 64 == 0).
  if (t < 128) {
    const int idx = rowBase + t;
    const int ci = idx < N_ROWS ? idx : N_ROWS - 1;
    const float4 bb = ((const float4*)pbox)[ci];
    rowcc[t] = (f32x4){bb.x, bb.y, bb.z, bb.w};
    rowxy[t] = (f32x4){fmaf(-0.5f, bb.z, bb.x), fmaf(-0.5f, bb.w, bb.y),
                       fmaf(0.5f, bb.z, bb.x), fmaf(0.5f, bb.w, bb.y)};
  } else if (t < 192) {
    const int c = t - 128;
    const float4 bb = ((const float4*)tbox)[colBase + c];
    colcc[c] = (f32x4){bb.x, bb.y, bb.z, bb.w};
    colxy[c] = (f32x4){fmaf(-0.5f, bb.z, bb.x), fmaf(-0.5f, bb.w, bb.y),
                       fmaf(0.5f, bb.z, bb.x), fmaf(0.5f, bb.w, bb.y)};
  }

  f32x4 acc[4][2];
#pragma unroll
  for (int i = 0; i < 4; ++i)
#pragma unroll
    for (int j = 0; j < 2; ++j) acc[i][j] = (f32x4){0.f, 0.f, 0.f, 0.f};

  // Pre-swizzled source granule: lane l stages granule (l&7)^(l>>3) so the
  // swizzled READ (g ^ row&7) sees linear data.
  const int swz = (lane & 7) ^ (lane >> 3);
  const int rbase = wid * 8 + (lane >> 3);   // staging row within 32-row group

  // K-loop: 4 tiles of BK=64.
  for (int kt = 0; kt < 4; ++kt) {
    const int k0 = kt * 64 + swz * 8;
#pragma unroll
    for (int i = 0; i < 4; ++i) {            // A: 128 rows
      int gr = rowBase + i * 32 + rbase;
      if (gr > N_ROWS - 1) gr = N_ROWS - 1;
      gload_lds16(probB + (size_t)gr * KDIM + k0, As + (i * 32 + wid * 8) * 64);
    }
#pragma unroll
    for (int i = 0; i < 2; ++i) {            // B: 64 rows (cols), no clamp
      const int gc = colBase + i * 32 + rbase;
      gload_lds16(embB + (size_t)gc * KDIM + k0, Bs + (i * 32 + wid * 8) * 64);
    }
    __syncthreads();
#pragma unroll
    for (int kk = 0; kk < 2; ++kk) {
      bf16x8 af[4], bfr[2];
      const int g = kk * 4 + (lane >> 4);    // 16B granule index 0..7
#pragma unroll
      for (int mi = 0; mi < 4; ++mi) {
        const int row = wr * 64 + mi * 16 + (lane & 15);
        af[mi] = *(const bf16x8*)(As + row * 64 + ((g ^ (row & 7)) * 8));
      }
#pragma unroll
      for (int ni = 0; ni < 2; ++ni) {
        const int row = wc * 32 + ni * 16 + (lane & 15);
        bfr[ni] = *(const bf16x8*)(Bs + row * 64 + ((g ^ (row & 7)) * 8));
      }
#pragma unroll
      for (int mi = 0; mi < 4; ++mi)
#pragma unroll
        for (int ni = 0; ni < 2; ++ni)
          acc[mi][ni] = __builtin_amdgcn_mfma_f32_16x16x32_bf16(
              af[mi], bfr[ni], acc[mi][ni], 0, 0, 0);
    }
    __syncthreads();   // last one also protects the tbuf overlay
  }

  // Fused epilogue. Per mi: compute+sigmoid -> tbuf[mi&1] (LDS transpose)
  // -> lgkm-only barrier -> coalesced dwordx4 NT stores (never drained).
  const float LOG2E = 1.44269504f;
  const int jr = (lane >> 4) * 4;   // row sub-offset for this lane group
  const int lc = lane & 15;
  f32x4 c0v[2], c1v[2];
  float cav[2];
#pragma unroll
  for (int ni = 0; ni < 2; ++ni) {
    const int cloc = wc * 32 + ni * 16 + lc;
    c0v[ni] = colcc[cloc];
    c1v[ni] = colxy[cloc];
    cav[ni] = c0v[ni][2] * c0v[ni][3];
  }

#pragma unroll
  for (int mi = 0; mi < 4; ++mi) {
    float* const tb = tbuf + (mi & 1) * 2176;   // 32*68 floats per buffer
#pragma unroll
    for (int j = 0; j < 4; ++j) {
      const int rloc = wr * 64 + mi * 16 + jr + j;
      const f32x4 r0 = rowcc[rloc];
      const f32x4 r1 = rowxy[rloc];
      const float ra = r0[2] * r0[3];
#pragma unroll
      for (int ni = 0; ni < 2; ++ni) {
        const f32x4 c0 = c0v[ni], c1 = c1v[ni];
        const float cc = fmaxf(acc[mi][ni][j], 0.0f);
        const float l1 = fabsf(r0[0] - c0[0]) + fabsf(r0[1] - c0[1]) +
                         fabsf(r0[2] - c0[2]) + fabsf(r0[3] - c0[3]);
        // Unclamped per-axis overlap; enclosing extent via sum identity.
        const float iwx = fminf(r1[2], c1[2]) - fmaxf(r1[0], c1[0]);
        const float iwy = fminf(r1[3], c1[3]) - fmaxf(r1[1], c1[1]);
        const float iw = fmaxf(iwx, 0.f);
        const float ih = fmaxf(iwy, 0.f);
        const float inter = iw * ih;
        const float uni = ra + cav[ni] - inter;
        const float ex = (r0[2] + c0[2]) - iwx;   // rw + cw - iwx
        const float ey = (r0[3] + c0[3]) - iwy;   // rh + ch - iwy
        const float earea = ex * ey;
        // inter/uni + uni/earea = (inter*earea + uni^2) / (uni*earea)
        const float num = fmaf(uni, uni, inter * earea);
        const float Cv = fmaf(-num, __builtin_amdgcn_rcpf(uni * earea),
                              l1 + cc + 1.0f);
        const float sg = __builtin_amdgcn_rcpf(
            1.0f + __builtin_amdgcn_exp2f(-LOG2E * Cv));
        tb[(wr * 16 + jr + j) * 68 + wc * 32 + ni * 16 + lc] = sg;
      }
    }
    // lgkm-only block barrier: LDS writes visible, NT stores keep streaming.
    asm volatile("s_waitcnt lgkmcnt(0)" ::: "memory");
    __builtin_amdgcn_s_barrier();
    // Read back transposed chunk (32 rows x 64 cols) and stream out.
#pragma unroll
    for (int rr = 0; rr < 2; ++rr) {
      const int rch = rr * 16 + (t >> 4);    // 0..31
      const int c4 = (t & 15) * 4;           // 0..60
      const f32x4 v = *(const f32x4*)(tb + rch * 68 + c4);
      const int grow = rowBase + ((rch < 16) ? (mi * 16 + rch)
                                             : (64 + mi * 16 + (rch - 16)));
      if (grow < N_ROWS)
        __builtin_nontemporal_store(
            v, (f32x4*)(out + (size_t)grow * M_COLS + colBase + c4));
    }
    // No second barrier: next mi writes the OTHER buffer; its pre-barrier
    // lgkmcnt(0) covers every wave's reads of this one.
  }
}

extern "C" void kernel_launch(void* const* d_in, const int* in_sizes, int n_in,
                              void* d_out, int out_size, void* d_ws, size_t ws_size,
                              hipStream_t stream) {
  const float* logits = (const float*)d_in[0];   // [16,900,256]
  const float* pbox   = (const float*)d_in[1];   // [16,900,4]
  const float* embs   = (const float*)d_in[2];   // [1600,256]
  const float* tbox   = (const float*)d_in[3];   // [1600,4]
  float* out = (float*)d_out;                    // [16,900,1600]

  short* probB = (short*)d_ws;                         // 14400*256 bf16
  short* embB  = probB + (size_t)N_ROWS * KDIM;        // 1600*256 bf16

  prep_kernel<<<(N_ROWS + M_COLS) / 4, 256, 0, stream>>>(logits, embs, probB, embB);

  cost_kernel<<<NWG, 256, 0, stream>>>(probB, embB, pbox, tbox, out);
}